// Round 5
// baseline (442.554 us; speedup 1.0000x reference)
//
#include <hip/hip_runtime.h>

typedef unsigned short u16;
typedef __attribute__((ext_vector_type(8))) short bf16x8;
typedef __attribute__((ext_vector_type(4))) float f32x4;
typedef __attribute__((ext_vector_type(8))) u16 u16x8;

#define GLOAD_LDS(g, s) __builtin_amdgcn_global_load_lds( \
    (const __attribute__((address_space(1))) void*)(g),   \
    (__attribute__((address_space(3))) void*)(s), 16, 0, 0)

__device__ __forceinline__ u16 f2bf(float f) {
  union { float f; unsigned u; } v; v.f = f;
  unsigned r = v.u + 0x7fffu + ((v.u >> 16) & 1u);
  return (u16)(r >> 16);
}
__device__ __forceinline__ float bf2f(u16 h) {
  union { unsigned u; float f; } v; v.u = ((unsigned)h) << 16;
  return v.f;
}

// ================= OLD 128x128 core (kept for k_proj only) =================
__device__ __forceinline__ void stage_pair(const u16* gA, int lda, const u16* gB, int ldb,
                                           u16* lA, u16* lB, int wave, int lane) {
  int row = (wave << 4) + (lane >> 2);
  int kb  = (lane & 3) << 3;
  GLOAD_LDS(gA + row * lda + kb,        lA + (wave << 9));
  GLOAD_LDS(gA + (row + 64) * lda + kb, lA + ((wave + 4) << 9));
  GLOAD_LDS(gB + row * ldb + kb,        lB + (wave << 9));
  GLOAD_LDS(gB + (row + 64) * ldb + kb, lB + ((wave + 4) << 9));
}

__device__ __forceinline__ void gemm_seg(f32x4 (&acc)[4][4],
    const u16* Ag, const u16* Bg, int lda, int ldb, int nk,
    u16* As, u16* Bs, int wave, int lane) {
  const int wr = (wave >> 1) << 6, wc = (wave & 1) << 6;
  const int rl = lane & 15, rk = (lane >> 4) << 3;
  stage_pair(Ag, lda, Bg, ldb, As, Bs, wave, lane);
  if (nk > 1)
    stage_pair(Ag + 32, lda, Bg + 32, ldb, As + 4096, Bs + 4096, wave, lane);
  int bufsel = 0;
  for (int kt = 0; kt < nk; ++kt) {
    if (kt + 1 < nk) asm volatile("s_waitcnt vmcnt(4)" ::: "memory");
    else             asm volatile("s_waitcnt vmcnt(0)" ::: "memory");
    __builtin_amdgcn_s_barrier();
    asm volatile("" ::: "memory");
    if (kt + 2 < nk) {
      int nb = bufsel + 2; if (nb >= 3) nb -= 3;
      stage_pair(Ag + (long)(kt + 2) * 32, lda, Bg + (long)(kt + 2) * 32, ldb,
                 As + nb * 4096, Bs + nb * 4096, wave, lane);
    }
    const u16* ab = As + bufsel * 4096;
    const u16* bb = Bs + bufsel * 4096;
    bf16x8 af[4], bfr[4];
#pragma unroll
    for (int i = 0; i < 4; i++)
      af[i]  = *(const bf16x8*)(ab + ((wr + (i << 4) + rl) << 5) + rk);
#pragma unroll
    for (int j = 0; j < 4; j++)
      bfr[j] = *(const bf16x8*)(bb + ((wc + (j << 4) + rl) << 5) + rk);
#pragma unroll
    for (int i = 0; i < 4; i++)
#pragma unroll
      for (int j = 0; j < 4; j++)
        acc[i][j] = __builtin_amdgcn_mfma_f32_16x16x32_bf16(af[i], bfr[j], acc[i][j], 0, 0, 0);
    __builtin_amdgcn_sched_barrier(0);
    bufsel = bufsel + 1; if (bufsel == 3) bufsel = 0;
  }
}

// ============ NEW 256x128 8-wave BK=64 2-phase-per-tile core ============
// LDS: As[2 buf][2 half][128 rows][64 k] = 64KB, Bs[2 buf][128][64] = 32KB.
// Swizzle: 16B-granule g stored at g ^ (row&7) (involution applied on the
// pre-swizzled global source of global_load_lds AND on the ds_read addr).

__device__ __forceinline__ void stage256(const u16* gA, int lda, const u16* gB, int ldb,
                                         u16* Ad, u16* Bd, int tid) {
  int rw = tid >> 3, g0 = tid & 7;
  int gs = (g0 ^ (rw & 7)) << 3;             // swizzled k-offset (elems)
  int wb = (tid >> 6) << 9;                  // wave-uniform LDS base (elems)
#pragma unroll
  for (int h = 0; h < 2; h++)
#pragma unroll
    for (int r = 0; r < 2; r++) {
      int row = h * 128 + r * 64 + rw;
      GLOAD_LDS(gA + (long)row * lda + gs, Ad + h * 8192 + r * 4096 + wb);
    }
#pragma unroll
  for (int r = 0; r < 2; r++) {
    int row = r * 64 + rw;
    GLOAD_LDS(gB + (long)row * ldb + gs, Bd + r * 4096 + wb);
  }
}

__device__ __forceinline__ void phase16(f32x4 (&acc)[4][4], const u16* ab, const u16* bb, int sw) {
  bf16x8 a[4], b[4];
#pragma unroll
  for (int i = 0; i < 4; i++) a[i] = *(const bf16x8*)(ab + i * 1024 + sw);
#pragma unroll
  for (int j = 0; j < 4; j++) b[j] = *(const bf16x8*)(bb + j * 1024 + sw);
  __builtin_amdgcn_s_barrier();
  asm volatile("s_waitcnt lgkmcnt(0)" ::: "memory");
  __builtin_amdgcn_sched_barrier(0);
  __builtin_amdgcn_s_setprio(1);
#pragma unroll
  for (int i = 0; i < 4; i++)
#pragma unroll
    for (int j = 0; j < 4; j++)
      acc[i][j] = __builtin_amdgcn_mfma_f32_16x16x32_bf16(a[i], b[j], acc[i][j], 0, 0, 0);
  __builtin_amdgcn_s_setprio(0);
  __builtin_amdgcn_sched_barrier(0);
}

// acc covers this wave's 64x64 sub-tile: rows mq*64, cols nh*64 of the 256x128 tile.
__device__ __forceinline__ void gemm256(f32x4 (&acc)[4][4],
    const u16* Ag, int lda, const u16* Bg, int ldb, int nk,
    u16* As, u16* Bs, int tid) {
  const int lane = tid & 63, wid = tid >> 6;
  const int mq = wid >> 1, nh = wid & 1;
  const int rl = lane & 15, kg = lane >> 4;
  const int swz0 = ((kg ^ (rl & 7)) << 3);
  const int rbA = (mq >> 1) * 8192 + ((mq & 1) * 64 + rl) * 64;
  const int rbB = (nh * 64 + rl) * 64;

  stage256(Ag, lda, Bg, ldb, As, Bs, tid);    // tile 0 -> buf 0
  asm volatile("s_waitcnt vmcnt(0)" ::: "memory");
  __builtin_amdgcn_s_barrier();
  for (int t = 0; t < nk; ++t) {
    const u16* ab = As + (t & 1) * 16384 + rbA;
    const u16* bb = Bs + (t & 1) * 8192 + rbB;
    if (t + 1 < nk)
      stage256(Ag + (t + 1) * 64, lda, Bg + (t + 1) * 64, ldb,
               As + ((t + 1) & 1) * 16384, Bs + ((t + 1) & 1) * 8192, tid);
    phase16(acc, ab, bb, swz0);               // kk=0
    __builtin_amdgcn_s_barrier();
    phase16(acc, ab, bb, swz0 ^ 32);          // kk=1
    if (t + 1 < nk) asm volatile("s_waitcnt vmcnt(0)" ::: "memory");
    __builtin_amdgcn_s_barrier();
  }
}

// ---------------- conversion kernels ----------------
__global__ __launch_bounds__(256) void k_cvt(const float* __restrict__ in,
                                             u16* __restrict__ out, int n8) {
  int i = blockIdx.x * 256 + threadIdx.x;
  if (i >= n8) return;
  const float4* pf = (const float4*)in + (long)i * 2;
  float4 a = pf[0], b = pf[1];
  u16x8 o;
  o[0] = f2bf(a.x); o[1] = f2bf(a.y); o[2] = f2bf(a.z); o[3] = f2bf(a.w);
  o[4] = f2bf(b.x); o[5] = f2bf(b.y); o[6] = f2bf(b.z); o[7] = f2bf(b.w);
  *((u16x8*)out + i) = o;
}

struct P6 { const float* p[6]; };
struct O6 { u16* p[6]; };

__global__ __launch_bounds__(256) void k_cvt_w(P6 w, u16* __restrict__ out) {
  int z = blockIdx.y;
  int i = blockIdx.x * 256 + threadIdx.x;
  const float4* pf = (const float4*)w.p[z] + (long)i * 2;
  float4 a = pf[0], b = pf[1];
  u16x8 o;
  o[0] = f2bf(a.x); o[1] = f2bf(a.y); o[2] = f2bf(a.z); o[3] = f2bf(a.w);
  o[4] = f2bf(b.x); o[5] = f2bf(b.y); o[6] = f2bf(b.z); o[7] = f2bf(b.w);
  *((u16x8*)(out + (long)z * 262144) + i) = o;
}

// ---------------- projections (old core) ----------------
__global__ __launch_bounds__(256) void k_proj(const u16* __restrict__ Xb, const u16* __restrict__ Yb,
                                              const u16* __restrict__ Wb, P6 bias, O6 dst) {
  __shared__ u16 As[12288], Bs[12288];
  int z = blockIdx.z, bm = blockIdx.x, bn = blockIdx.y;
  int tid = threadIdx.x, wave = tid >> 6, lane = tid & 63;
  const u16* Ag = (z < 3 ? Xb : Yb) + (long)bm * 128 * 512;
  const u16* Bg = Wb + (long)z * 262144 + (long)bn * 128 * 512;
  f32x4 acc[4][4] = {};
  gemm_seg(acc, Ag, Bg, 512, 512, 16, As, Bs, wave, lane);
  const float* bi = bias.p[z];
  u16* D = dst.p[z];
  int wr = (wave >> 1) << 6, wc = (wave & 1) << 6;
  int row0 = bm * 128 + wr + ((lane >> 4) << 2);
  int col0 = bn * 128 + wc + (lane & 15);
  float bj[4];
#pragma unroll
  for (int j = 0; j < 4; j++) bj[j] = bi[col0 + (j << 4)];
#pragma unroll
  for (int i = 0; i < 4; i++)
#pragma unroll
    for (int j = 0; j < 4; j++)
#pragma unroll
      for (int r = 0; r < 4; r++)
        D[(long)(row0 + (i << 4) + r) * 512 + col0 + (j << 4)] = f2bf(acc[i][j][r] + bj[j]);
}

// ---------------- scores (new core): S[b,n,m] tile 256x128 ----------------
__global__ __launch_bounds__(512) void k_s(const u16* __restrict__ Q, const u16* __restrict__ K,
                                           u16* __restrict__ S) {
  __shared__ u16 As[32768], Bs[16384];
  int x = blockIdx.x;
  int bn = x & 15, bm = (x >> 4) & 7, b = x >> 7;
  int tid = threadIdx.x;
  const u16* Ag = Q + (long)b * 1048576 + (long)bm * 256 * 512;
  const u16* Bg = K + (long)b * 1048576 + (long)bn * 128 * 512;
  f32x4 acc[4][4] = {};
  gemm256(acc, Ag, 512, Bg, 512, 8, As, Bs, tid);
  u16* D = S + (long)b * 4194304;
  const float scale = 0.04419417382415922f;  // 1/sqrt(512)
  int lane = tid & 63, wid = tid >> 6;
  int mq = wid >> 1, nh = wid & 1;
  int row0 = bm * 256 + mq * 64 + ((lane >> 4) << 2);
  int col0 = bn * 128 + nh * 64 + (lane & 15);
#pragma unroll
  for (int i = 0; i < 4; i++)
#pragma unroll
    for (int j = 0; j < 4; j++)
#pragma unroll
      for (int r = 0; r < 4; r++)
        D[(long)(row0 + (i << 4) + r) * 2048 + col0 + (j << 4)] = f2bf(acc[i][j][r] * scale);
}

// ---------------- softmax over batch axis ----------------
__global__ __launch_bounds__(256) void k_softmax(u16* __restrict__ S) {
  int idx = blockIdx.x * 256 + threadIdx.x;
  u16x8 v[8];
#pragma unroll
  for (int b = 0; b < 8; b++) v[b] = *((const u16x8*)(S + (long)b * 4194304) + idx);
#pragma unroll
  for (int j = 0; j < 8; j++) {
    float e[8], m = -1e30f;
#pragma unroll
    for (int b = 0; b < 8; b++) { e[b] = bf2f(v[b][j]); m = fmaxf(m, e[b]); }
    float s = 0.f;
#pragma unroll
    for (int b = 0; b < 8; b++) { e[b] = __expf(e[b] - m); s += e[b]; }
    float inv = 1.0f / s;
#pragma unroll
    for (int b = 0; b < 8; b++) v[b][j] = f2bf(e[b] * inv);
  }
#pragma unroll
  for (int b = 0; b < 8; b++) *((u16x8*)(S + (long)b * 4194304) + idx) = v[b];
}

// ---------------- V transpose ----------------
__global__ __launch_bounds__(256) void k_tr(const u16* __restrict__ V1, const u16* __restrict__ V2,
                                            u16* __restrict__ T1, u16* __restrict__ T2) {
  __shared__ u16 tile[64][65];
  int z = blockIdx.z;
  const u16* src = (z < 8 ? V1 : V2) + (long)(z & 7) * 1048576;
  u16*       dst = (z < 8 ? T1 : T2) + (long)(z & 7) * 1048576;
  int n0 = blockIdx.x * 64, d0 = blockIdx.y * 64;
  int t = threadIdx.x;
  int r = t >> 2, cs = (t & 3) * 16;
  const u16x8* sp = (const u16x8*)(src + (long)(n0 + r) * 512 + d0 + cs);
  u16x8 a = sp[0], b = sp[1];
#pragma unroll
  for (int jj = 0; jj < 8; jj++) { tile[r][cs + jj] = a[jj]; tile[r][cs + 8 + jj] = b[jj]; }
  __syncthreads();
  u16x8 o0, o1;
#pragma unroll
  for (int jj = 0; jj < 8; jj++) { o0[jj] = tile[cs + jj][r]; o1[jj] = tile[cs + 8 + jj][r]; }
  u16x8* op = (u16x8*)(dst + (long)(d0 + r) * 2048 + n0 + cs);
  op[0] = o0; op[1] = o1;
}

// ---------------- PV (new core, full K): out tile 256x128 ----------------
// mode 0: out = acc + X + Y ; mode 1: out += acc
__global__ __launch_bounds__(512) void k_pv(const u16* __restrict__ A, const u16* __restrict__ Vt,
                                            const float* __restrict__ X, const float* __restrict__ Y,
                                            float* __restrict__ out, int mode) {
  __shared__ u16 As[32768], Bs[16384];
  int x = blockIdx.x;
  int bn = x & 3, bm = (x >> 2) & 7, b = x >> 5;
  int tid = threadIdx.x;
  const u16* Ag = A + (long)b * 4194304 + (long)bm * 256 * 2048;
  const u16* Bg = Vt + (long)b * 1048576 + (long)bn * 128 * 2048;
  f32x4 acc[4][4] = {};
  gemm256(acc, Ag, 2048, Bg, 2048, 32, As, Bs, tid);
  int lane = tid & 63, wid = tid >> 6;
  int mq = wid >> 1, nh = wid & 1;
  int row0 = bm * 256 + mq * 64 + ((lane >> 4) << 2);
  int col0 = bn * 128 + nh * 64 + (lane & 15);
  long base = (long)b * 1048576;
#pragma unroll
  for (int i = 0; i < 4; i++)
#pragma unroll
    for (int j = 0; j < 4; j++)
#pragma unroll
      for (int r = 0; r < 4; r++) {
        long idx = base + (long)(row0 + (i << 4) + r) * 512 + col0 + (j << 4);
        float v = acc[i][j][r];
        out[idx] = mode ? (out[idx] + v) : (v + X[idx] + Y[idx]);
      }
}

extern "C" void kernel_launch(void* const* d_in, const int* in_sizes, int n_in,
                              void* d_out, int out_size, void* d_ws, size_t ws_size,
                              hipStream_t stream) {
  const float* X = (const float*)d_in[0];
  const float* Y = (const float*)d_in[1];
  P6 wp, bp;
  for (int i = 0; i < 6; i++) { wp.p[i] = (const float*)d_in[2 + 2 * i]; bp.p[i] = (const float*)d_in[3 + 2 * i]; }

  const long NX = 8L * 2048 * 512;
  const long NS = 8L * 2048 * 2048;
  u16* p = (u16*)d_ws;
  u16* Xb = p;  p += NX;                  // bf16 X (reused as Vt1)
  u16* Yb = p;  p += NX;                  // bf16 Y (reused as Vt2)
  u16* Wb = p;  p += 6L * 512 * 512;
  u16* Q1 = p;  p += NX;
  u16* K2 = p;  p += NX;
  u16* Q2 = p;  p += NX;
  u16* K1 = p;  p += NX;
  u16* Sb = p;  p += NS;
  u16* V1 = Sb;
  u16* V2 = Sb + NX;
  u16* Vt1 = Xb;
  u16* Vt2 = Yb;
  (void)ws_size; (void)in_sizes; (void)n_in; (void)out_size;

  dim3 T(256);
  k_cvt<<<dim3(4096), T, 0, stream>>>(X, Xb, (int)(NX / 8));
  k_cvt<<<dim3(4096), T, 0, stream>>>(Y, Yb, (int)(NX / 8));
  k_cvt_w<<<dim3(128, 6), T, 0, stream>>>(wp, Wb);
  O6 dst; dst.p[0] = Q1; dst.p[1] = K1; dst.p[2] = V1; dst.p[3] = Q2; dst.p[4] = K2; dst.p[5] = V2;
  k_proj<<<dim3(128, 4, 6), T, 0, stream>>>(Xb, Yb, Wb, bp, dst);
  k_tr<<<dim3(32, 8, 16), T, 0, stream>>>(V1, V2, Vt1, Vt2);
  // attention 2 first: S2 = Q2.K1^T, softmax over b, out = A2.V1 + X + Y
  k_s<<<dim3(1024), dim3(512), 0, stream>>>(Q2, K1, Sb);
  k_softmax<<<dim3(2048), T, 0, stream>>>(Sb);
  k_pv<<<dim3(256), dim3(512), 0, stream>>>(Sb, Vt1, X, Y, (float*)d_out, 0);
  // attention 1: S1 = Q1.K2^T, softmax, out += A1.V2
  k_s<<<dim3(1024), dim3(512), 0, stream>>>(Q1, K2, Sb);
  k_softmax<<<dim3(2048), T, 0, stream>>>(Sb);
  k_pv<<<dim3(256), dim3(512), 0, stream>>>(Sb, Vt2, X, Y, (float*)d_out, 1);
}

// Round 6
// 398.535 us; speedup vs baseline: 1.1105x; 1.1105x over previous
//
#include <hip/hip_runtime.h>

typedef unsigned short u16;
typedef __attribute__((ext_vector_type(8))) short bf16x8;
typedef __attribute__((ext_vector_type(4))) float f32x4;
typedef __attribute__((ext_vector_type(8))) u16 u16x8;

#define GLOAD_LDS(g, s) __builtin_amdgcn_global_load_lds( \
    (const __attribute__((address_space(1))) void*)(g),   \
    (__attribute__((address_space(3))) void*)(s), 16, 0, 0)

__device__ __forceinline__ u16 f2bf(float f) {
  union { float f; unsigned u; } v; v.f = f;
  unsigned r = v.u + 0x7fffu + ((v.u >> 16) & 1u);
  return (u16)(r >> 16);
}
__device__ __forceinline__ float bf2f(u16 h) {
  union { unsigned u; float f; } v; v.u = ((unsigned)h) << 16;
  return v.f;
}

// ================= OLD 128x128 core (k_proj only) =================
__device__ __forceinline__ void stage_pair(const u16* gA, int lda, const u16* gB, int ldb,
                                           u16* lA, u16* lB, int wave, int lane) {
  int row = (wave << 4) + (lane >> 2);
  int kb  = (lane & 3) << 3;
  GLOAD_LDS(gA + row * lda + kb,        lA + (wave << 9));
  GLOAD_LDS(gA + (row + 64) * lda + kb, lA + ((wave + 4) << 9));
  GLOAD_LDS(gB + row * ldb + kb,        lB + (wave << 9));
  GLOAD_LDS(gB + (row + 64) * ldb + kb, lB + ((wave + 4) << 9));
}

__device__ __forceinline__ void gemm_seg(f32x4 (&acc)[4][4],
    const u16* Ag, const u16* Bg, int lda, int ldb, int nk,
    u16* As, u16* Bs, int wave, int lane) {
  const int wr = (wave >> 1) << 6, wc = (wave & 1) << 6;
  const int rl = lane & 15, rk = (lane >> 4) << 3;
  stage_pair(Ag, lda, Bg, ldb, As, Bs, wave, lane);
  if (nk > 1)
    stage_pair(Ag + 32, lda, Bg + 32, ldb, As + 4096, Bs + 4096, wave, lane);
  int bufsel = 0;
  for (int kt = 0; kt < nk; ++kt) {
    if (kt + 1 < nk) asm volatile("s_waitcnt vmcnt(4)" ::: "memory");
    else             asm volatile("s_waitcnt vmcnt(0)" ::: "memory");
    __builtin_amdgcn_s_barrier();
    asm volatile("" ::: "memory");
    if (kt + 2 < nk) {
      int nb = bufsel + 2; if (nb >= 3) nb -= 3;
      stage_pair(Ag + (long)(kt + 2) * 32, lda, Bg + (long)(kt + 2) * 32, ldb,
                 As + nb * 4096, Bs + nb * 4096, wave, lane);
    }
    const u16* ab = As + bufsel * 4096;
    const u16* bb = Bs + bufsel * 4096;
    bf16x8 af[4], bfr[4];
#pragma unroll
    for (int i = 0; i < 4; i++)
      af[i]  = *(const bf16x8*)(ab + ((wr + (i << 4) + rl) << 5) + rk);
#pragma unroll
    for (int j = 0; j < 4; j++)
      bfr[j] = *(const bf16x8*)(bb + ((wc + (j << 4) + rl) << 5) + rk);
#pragma unroll
    for (int i = 0; i < 4; i++)
#pragma unroll
      for (int j = 0; j < 4; j++)
        acc[i][j] = __builtin_amdgcn_mfma_f32_16x16x32_bf16(af[i], bfr[j], acc[i][j], 0, 0, 0);
    __builtin_amdgcn_sched_barrier(0);
    bufsel = bufsel + 1; if (bufsel == 3) bufsel = 0;
  }
}

// ============ 256x128 8-wave BK=64 core, 3-buffer never-drain ============
// LDS: As[3][2 half][2 sub][64 rows][64 k] = 96KB, Bs[3][128][64] = 48KB.
// Swizzle: 16B granule g stored at g ^ (row&7), applied on the pre-swizzled
// global source of global_load_lds AND on the ds_read address (involution).
// Pipeline: stage(t+2) issued at tile t; steady wait = vmcnt(6) (stage t
// landed, stage t+1 in flight); one barrier per tile; drain only at tail.

__device__ __forceinline__ void stage256(const u16* gA, int lda, const u16* gB, int ldb,
                                         u16* Ad, u16* Bd, int tid) {
  int rw = tid >> 3, g0 = tid & 7;
  int gs = (g0 ^ (rw & 7)) << 3;             // swizzled k-offset (elems)
  int wb = (tid >> 6) << 9;                  // wave-uniform LDS base (elems)
#pragma unroll
  for (int h = 0; h < 2; h++)
#pragma unroll
    for (int r = 0; r < 2; r++) {
      int row = h * 128 + r * 64 + rw;
      GLOAD_LDS(gA + (long)row * lda + gs, Ad + h * 8192 + r * 4096 + wb);
    }
#pragma unroll
  for (int r = 0; r < 2; r++) {
    int row = r * 64 + rw;
    GLOAD_LDS(gB + (long)row * ldb + gs, Bd + r * 4096 + wb);
  }
}

__device__ __forceinline__ void phase16(f32x4 (&acc)[4][4], const u16* ab, const u16* bb, int sw) {
  bf16x8 a[4], b[4];
#pragma unroll
  for (int i = 0; i < 4; i++) a[i] = *(const bf16x8*)(ab + i * 1024 + sw);
#pragma unroll
  for (int j = 0; j < 4; j++) b[j] = *(const bf16x8*)(bb + j * 1024 + sw);
  asm volatile("s_waitcnt lgkmcnt(0)" ::: "memory");
  __builtin_amdgcn_sched_barrier(0);
  __builtin_amdgcn_s_setprio(1);
#pragma unroll
  for (int i = 0; i < 4; i++)
#pragma unroll
    for (int j = 0; j < 4; j++)
      acc[i][j] = __builtin_amdgcn_mfma_f32_16x16x32_bf16(a[i], b[j], acc[i][j], 0, 0, 0);
  __builtin_amdgcn_s_setprio(0);
  __builtin_amdgcn_sched_barrier(0);
}

__device__ __forceinline__ void gemm256(f32x4 (&acc)[4][4],
    const u16* Ag, int lda, const u16* Bg, int ldb, int nk,
    u16* As, u16* Bs, int tid) {
  const int lane = tid & 63, wid = tid >> 6;
  const int mq = wid >> 1, nh = wid & 1;
  const int rl = lane & 15, kg = lane >> 4;
  const int swz0 = ((kg ^ (rl & 7)) << 3);
  const int rbA = (mq >> 1) * 8192 + ((mq & 1) * 64 + rl) * 64;
  const int rbB = (nh * 64 + rl) * 64;

  stage256(Ag, lda, Bg, ldb, As, Bs, tid);                       // t=0 -> buf0
  if (nk > 1)
    stage256(Ag + 64, lda, Bg + 64, ldb, As + 16384, Bs + 8192, tid); // t=1 -> buf1
  int bsel = 0;
  for (int t = 0; t < nk; ++t) {
    if (t + 1 < nk) asm volatile("s_waitcnt vmcnt(6)" ::: "memory");
    else            asm volatile("s_waitcnt vmcnt(0)" ::: "memory");
    __builtin_amdgcn_s_barrier();              // all waves: stage(t) landed,
    asm volatile("" ::: "memory");             // tile t-1 LDS reads drained
    if (t + 2 < nk) {
      int nb = bsel + 2; if (nb >= 3) nb -= 3;
      stage256(Ag + (long)(t + 2) * 64, lda, Bg + (long)(t + 2) * 64, ldb,
               As + nb * 16384, Bs + nb * 8192, tid);
    }
    const u16* ab = As + bsel * 16384 + rbA;
    const u16* bb = Bs + bsel * 8192 + rbB;
    phase16(acc, ab, bb, swz0);                // kk=0 (no barrier needed inside)
    phase16(acc, ab, bb, swz0 ^ 32);           // kk=1 (same buffer, no hazard)
    bsel = bsel + 1; if (bsel == 3) bsel = 0;
  }
}

// ---------------- conversion kernels ----------------
__global__ __launch_bounds__(256) void k_cvt(const float* __restrict__ in,
                                             u16* __restrict__ out, int n8) {
  int i = blockIdx.x * 256 + threadIdx.x;
  if (i >= n8) return;
  const float4* pf = (const float4*)in + (long)i * 2;
  float4 a = pf[0], b = pf[1];
  u16x8 o;
  o[0] = f2bf(a.x); o[1] = f2bf(a.y); o[2] = f2bf(a.z); o[3] = f2bf(a.w);
  o[4] = f2bf(b.x); o[5] = f2bf(b.y); o[6] = f2bf(b.z); o[7] = f2bf(b.w);
  *((u16x8*)out + i) = o;
}

struct P6 { const float* p[6]; };
struct O6 { u16* p[6]; };

__global__ __launch_bounds__(256) void k_cvt_w(P6 w, u16* __restrict__ out) {
  int z = blockIdx.y;
  int i = blockIdx.x * 256 + threadIdx.x;
  const float4* pf = (const float4*)w.p[z] + (long)i * 2;
  float4 a = pf[0], b = pf[1];
  u16x8 o;
  o[0] = f2bf(a.x); o[1] = f2bf(a.y); o[2] = f2bf(a.z); o[3] = f2bf(a.w);
  o[4] = f2bf(b.x); o[5] = f2bf(b.y); o[6] = f2bf(b.z); o[7] = f2bf(b.w);
  *((u16x8*)(out + (long)z * 262144) + i) = o;
}

// ---------------- projections (old core, 1D bm-chunked grid) ----------------
// 3072 blocks: XCD chunk = 16 consecutive bm (W 3MB stays L2-resident/XCD;
// X/Y bm-panel shared by 12 consecutive blocks).
__global__ __launch_bounds__(256) void k_proj(const u16* __restrict__ Xb, const u16* __restrict__ Yb,
                                              const u16* __restrict__ Wb, P6 bias, O6 dst) {
  __shared__ u16 As[12288], Bs[12288];
  int x = blockIdx.x;
  int swz = (x & 7) * 384 + (x >> 3);
  int bm = swz / 24;
  int r  = swz - bm * 24;
  int z = r >> 2, bn = r & 3;
  int tid = threadIdx.x, wave = tid >> 6, lane = tid & 63;
  const u16* Ag = (z < 3 ? Xb : Yb) + (long)bm * 128 * 512;
  const u16* Bg = Wb + (long)z * 262144 + (long)bn * 128 * 512;
  f32x4 acc[4][4] = {};
  gemm_seg(acc, Ag, Bg, 512, 512, 16, As, Bs, wave, lane);
  const float* bi = bias.p[z];
  u16* D = dst.p[z];
  int wr = (wave >> 1) << 6, wc = (wave & 1) << 6;
  int row0 = bm * 128 + wr + ((lane >> 4) << 2);
  int col0 = bn * 128 + wc + (lane & 15);
  float bj[4];
#pragma unroll
  for (int j = 0; j < 4; j++) bj[j] = bi[col0 + (j << 4)];
#pragma unroll
  for (int i = 0; i < 4; i++)
#pragma unroll
    for (int j = 0; j < 4; j++)
#pragma unroll
      for (int rr = 0; rr < 4; rr++)
        D[(long)(row0 + (i << 4) + rr) * 512 + col0 + (j << 4)] = f2bf(acc[i][j][rr] + bj[j]);
}

// ---------------- scores (new core): XCD chunk = one batch b ----------------
__global__ __launch_bounds__(512) void k_s(const u16* __restrict__ Q, const u16* __restrict__ K,
                                           u16* __restrict__ S) {
  __shared__ u16 As[49152], Bs[24576];
  int x = blockIdx.x;
  int swz = (x & 7) * 128 + (x >> 3);        // 1024 blocks, chunk=128 = one b
  int bn = swz & 15, bm = (swz >> 4) & 7, b = swz >> 7;
  int tid = threadIdx.x;
  const u16* Ag = Q + (long)b * 1048576 + (long)bm * 256 * 512;
  const u16* Bg = K + (long)b * 1048576 + (long)bn * 128 * 512;
  f32x4 acc[4][4] = {};
  gemm256(acc, Ag, 512, Bg, 512, 8, As, Bs, tid);
  u16* D = S + (long)b * 4194304;
  const float scale = 0.04419417382415922f;  // 1/sqrt(512)
  int lane = tid & 63, wid = tid >> 6;
  int mq = wid >> 1, nh = wid & 1;
  int row0 = bm * 256 + mq * 64 + ((lane >> 4) << 2);
  int col0 = bn * 128 + nh * 64 + (lane & 15);
#pragma unroll
  for (int i = 0; i < 4; i++)
#pragma unroll
    for (int j = 0; j < 4; j++)
#pragma unroll
      for (int rr = 0; rr < 4; rr++)
        D[(long)(row0 + (i << 4) + rr) * 2048 + col0 + (j << 4)] = f2bf(acc[i][j][rr] * scale);
}

// ---------------- softmax over batch axis ----------------
__global__ __launch_bounds__(256) void k_softmax(u16* __restrict__ S) {
  int idx = blockIdx.x * 256 + threadIdx.x;
  u16x8 v[8];
#pragma unroll
  for (int b = 0; b < 8; b++) v[b] = *((const u16x8*)(S + (long)b * 4194304) + idx);
#pragma unroll
  for (int j = 0; j < 8; j++) {
    float e[8], m = -1e30f;
#pragma unroll
    for (int b = 0; b < 8; b++) { e[b] = bf2f(v[b][j]); m = fmaxf(m, e[b]); }
    float s = 0.f;
#pragma unroll
    for (int b = 0; b < 8; b++) { e[b] = __expf(e[b] - m); s += e[b]; }
    float inv = 1.0f / s;
#pragma unroll
    for (int b = 0; b < 8; b++) v[b][j] = f2bf(e[b] * inv);
  }
#pragma unroll
  for (int b = 0; b < 8; b++) *((u16x8*)(S + (long)b * 4194304) + idx) = v[b];
}

// ---------------- V transpose ----------------
__global__ __launch_bounds__(256) void k_tr(const u16* __restrict__ V1, const u16* __restrict__ V2,
                                            u16* __restrict__ T1, u16* __restrict__ T2) {
  __shared__ u16 tile[64][65];
  int z = blockIdx.z;
  const u16* src = (z < 8 ? V1 : V2) + (long)(z & 7) * 1048576;
  u16*       dst = (z < 8 ? T1 : T2) + (long)(z & 7) * 1048576;
  int n0 = blockIdx.x * 64, d0 = blockIdx.y * 64;
  int t = threadIdx.x;
  int r = t >> 2, cs = (t & 3) * 16;
  const u16x8* sp = (const u16x8*)(src + (long)(n0 + r) * 512 + d0 + cs);
  u16x8 a = sp[0], b = sp[1];
#pragma unroll
  for (int jj = 0; jj < 8; jj++) { tile[r][cs + jj] = a[jj]; tile[r][cs + 8 + jj] = b[jj]; }
  __syncthreads();
  u16x8 o0, o1;
#pragma unroll
  for (int jj = 0; jj < 8; jj++) { o0[jj] = tile[cs + jj][r]; o1[jj] = tile[cs + 8 + jj][r]; }
  u16x8* op = (u16x8*)(dst + (long)(d0 + r) * 2048 + n0 + cs);
  op[0] = o0; op[1] = o1;
}

// ---------------- PV (new core): XCD chunk = one batch b ----------------
// mode 0: out = acc + X + Y ; mode 1: out += acc
__global__ __launch_bounds__(512) void k_pv(const u16* __restrict__ A, const u16* __restrict__ Vt,
                                            const float* __restrict__ X, const float* __restrict__ Y,
                                            float* __restrict__ out, int mode) {
  __shared__ u16 As[49152], Bs[24576];
  int x = blockIdx.x;
  int swz = (x & 7) * 32 + (x >> 3);         // 256 blocks, chunk=32 = one b
  int bn = swz & 3, bm = (swz >> 2) & 7, b = swz >> 5;
  int tid = threadIdx.x;
  const u16* Ag = A + (long)b * 4194304 + (long)bm * 256 * 2048;
  const u16* Bg = Vt + (long)b * 1048576 + (long)bn * 128 * 2048;
  f32x4 acc[4][4] = {};
  gemm256(acc, Ag, 2048, Bg, 2048, 32, As, Bs, tid);
  int lane = tid & 63, wid = tid >> 6;
  int mq = wid >> 1, nh = wid & 1;
  int row0 = bm * 256 + mq * 64 + ((lane >> 4) << 2);
  int col0 = bn * 128 + nh * 64 + (lane & 15);
  long base = (long)b * 1048576;
#pragma unroll
  for (int i = 0; i < 4; i++)
#pragma unroll
    for (int j = 0; j < 4; j++)
#pragma unroll
      for (int rr = 0; rr < 4; rr++) {
        long idx = base + (long)(row0 + (i << 4) + rr) * 512 + col0 + (j << 4);
        float v = acc[i][j][rr];
        out[idx] = mode ? (out[idx] + v) : (v + X[idx] + Y[idx]);
      }
}

extern "C" void kernel_launch(void* const* d_in, const int* in_sizes, int n_in,
                              void* d_out, int out_size, void* d_ws, size_t ws_size,
                              hipStream_t stream) {
  const float* X = (const float*)d_in[0];
  const float* Y = (const float*)d_in[1];
  P6 wp, bp;
  for (int i = 0; i < 6; i++) { wp.p[i] = (const float*)d_in[2 + 2 * i]; bp.p[i] = (const float*)d_in[3 + 2 * i]; }

  const long NX = 8L * 2048 * 512;
  const long NS = 8L * 2048 * 2048;
  u16* p = (u16*)d_ws;
  u16* Xb = p;  p += NX;                  // bf16 X (reused as Vt1)
  u16* Yb = p;  p += NX;                  // bf16 Y (reused as Vt2)
  u16* Wb = p;  p += 6L * 512 * 512;
  u16* Q1 = p;  p += NX;
  u16* K2 = p;  p += NX;
  u16* Q2 = p;  p += NX;
  u16* K1 = p;  p += NX;
  u16* Sb = p;  p += NS;
  u16* V1 = Sb;
  u16* V2 = Sb + NX;
  u16* Vt1 = Xb;
  u16* Vt2 = Yb;
  (void)ws_size; (void)in_sizes; (void)n_in; (void)out_size;

  dim3 T(256);
  k_cvt<<<dim3(4096), T, 0, stream>>>(X, Xb, (int)(NX / 8));
  k_cvt<<<dim3(4096), T, 0, stream>>>(Y, Yb, (int)(NX / 8));
  k_cvt_w<<<dim3(128, 6), T, 0, stream>>>(wp, Wb);
  O6 dst; dst.p[0] = Q1; dst.p[1] = K1; dst.p[2] = V1; dst.p[3] = Q2; dst.p[4] = K2; dst.p[5] = V2;
  k_proj<<<dim3(3072), T, 0, stream>>>(Xb, Yb, Wb, bp, dst);
  k_tr<<<dim3(32, 8, 16), T, 0, stream>>>(V1, V2, Vt1, Vt2);
  // attention 2 first: S2 = Q2.K1^T, softmax over b, out = A2.V1 + X + Y
  k_s<<<dim3(1024), dim3(512), 0, stream>>>(Q2, K1, Sb);
  k_softmax<<<dim3(2048), T, 0, stream>>>(Sb);
  k_pv<<<dim3(256), dim3(512), 0, stream>>>(Sb, Vt1, X, Y, (float*)d_out, 0);
  // attention 1: S1 = Q1.K2^T, softmax, out += A1.V2
  k_s<<<dim3(1024), dim3(512), 0, stream>>>(Q1, K2, Sb);
  k_softmax<<<dim3(2048), T, 0, stream>>>(Sb);
  k_pv<<<dim3(256), dim3(512), 0, stream>>>(Sb, Vt2, X, Y, (float*)d_out, 1);
}

// Round 7
// 362.053 us; speedup vs baseline: 1.2223x; 1.1008x over previous
//
#include <hip/hip_runtime.h>

typedef unsigned short u16;
typedef __attribute__((ext_vector_type(8))) short bf16x8;
typedef __attribute__((ext_vector_type(4))) float f32x4;
typedef __attribute__((ext_vector_type(8))) u16 u16x8;

#define GLOAD_LDS(g, s) __builtin_amdgcn_global_load_lds( \
    (const __attribute__((address_space(1))) void*)(g),   \
    (__attribute__((address_space(3))) void*)(s), 16, 0, 0)

__device__ __forceinline__ u16 f2bf(float f) {
  union { float f; unsigned u; } v; v.f = f;
  unsigned r = v.u + 0x7fffu + ((v.u >> 16) & 1u);
  return (u16)(r >> 16);
}
__device__ __forceinline__ float bf2f(u16 h) {
  union { unsigned u; float f; } v; v.u = ((unsigned)h) << 16;
  return v.f;
}

// inline-asm ds_read_b128: invisible to compiler waitcnt insertion; we count
// lgkmcnt by hand (rule #18: lgkmcnt asm + sched_barrier before consumers).
__device__ __forceinline__ unsigned lds_a(const u16* p) {
  return (unsigned)(unsigned long long)(__attribute__((address_space(3))) const u16*)p;
}
__device__ __forceinline__ bf16x8 ds128(const u16* p) {
  bf16x8 r;
  asm volatile("ds_read_b128 %0, %1" : "=v"(r) : "v"(lds_a(p)));
  return r;
}

// ================= OLD 128x128 core (k_proj only) =================
__device__ __forceinline__ void stage_pair(const u16* gA, int lda, const u16* gB, int ldb,
                                           u16* lA, u16* lB, int wave, int lane) {
  int row = (wave << 4) + (lane >> 2);
  int kb  = (lane & 3) << 3;
  GLOAD_LDS(gA + row * lda + kb,        lA + (wave << 9));
  GLOAD_LDS(gA + (row + 64) * lda + kb, lA + ((wave + 4) << 9));
  GLOAD_LDS(gB + row * ldb + kb,        lB + (wave << 9));
  GLOAD_LDS(gB + (row + 64) * ldb + kb, lB + ((wave + 4) << 9));
}

__device__ __forceinline__ void gemm_seg(f32x4 (&acc)[4][4],
    const u16* Ag, const u16* Bg, int lda, int ldb, int nk,
    u16* As, u16* Bs, int wave, int lane) {
  const int wr = (wave >> 1) << 6, wc = (wave & 1) << 6;
  const int rl = lane & 15, rk = (lane >> 4) << 3;
  stage_pair(Ag, lda, Bg, ldb, As, Bs, wave, lane);
  if (nk > 1)
    stage_pair(Ag + 32, lda, Bg + 32, ldb, As + 4096, Bs + 4096, wave, lane);
  int bufsel = 0;
  for (int kt = 0; kt < nk; ++kt) {
    if (kt + 1 < nk) asm volatile("s_waitcnt vmcnt(4)" ::: "memory");
    else             asm volatile("s_waitcnt vmcnt(0)" ::: "memory");
    __builtin_amdgcn_s_barrier();
    asm volatile("" ::: "memory");
    if (kt + 2 < nk) {
      int nb = bufsel + 2; if (nb >= 3) nb -= 3;
      stage_pair(Ag + (long)(kt + 2) * 32, lda, Bg + (long)(kt + 2) * 32, ldb,
                 As + nb * 4096, Bs + nb * 4096, wave, lane);
    }
    const u16* ab = As + bufsel * 4096;
    const u16* bb = Bs + bufsel * 4096;
    bf16x8 af[4], bfr[4];
#pragma unroll
    for (int i = 0; i < 4; i++)
      af[i]  = *(const bf16x8*)(ab + ((wr + (i << 4) + rl) << 5) + rk);
#pragma unroll
    for (int j = 0; j < 4; j++)
      bfr[j] = *(const bf16x8*)(bb + ((wc + (j << 4) + rl) << 5) + rk);
#pragma unroll
    for (int i = 0; i < 4; i++)
#pragma unroll
      for (int j = 0; j < 4; j++)
        acc[i][j] = __builtin_amdgcn_mfma_f32_16x16x32_bf16(af[i], bfr[j], acc[i][j], 0, 0, 0);
    __builtin_amdgcn_sched_barrier(0);
    bufsel = bufsel + 1; if (bufsel == 3) bufsel = 0;
  }
}

// ============ 256x128 8-wave BK=64 core, 3-buffer never-drain ============
// LDS: As[3][2 half][2 sub][64 rows][64 k] = 96KB, Bs[3][128][64] = 48KB.
// Swizzle: 16B granule g stored at g ^ (row&7) (pre-swizzled global source
// of global_load_lds AND on the ds_read address — involution, 0 conflicts,
// verified round 5/6). Pipeline: stage(t+2) at tile t; steady vmcnt(6);
// ONE barrier per tile; asm ds_read_b128 with counted lgkmcnt.

__device__ __forceinline__ void stage256(const u16* gA, int lda, const u16* gB, int ldb,
                                         u16* Ad, u16* Bd, int tid) {
  int rw = tid >> 3, g0 = tid & 7;
  int gs = (g0 ^ (rw & 7)) << 3;             // swizzled k-offset (elems)
  int wb = (tid >> 6) << 9;                  // wave-uniform LDS base (elems)
#pragma unroll
  for (int h = 0; h < 2; h++)
#pragma unroll
    for (int r = 0; r < 2; r++) {
      int row = h * 128 + r * 64 + rw;
      GLOAD_LDS(gA + (long)row * lda + gs, Ad + h * 8192 + r * 4096 + wb);
    }
#pragma unroll
  for (int r = 0; r < 2; r++) {
    int row = r * 64 + rw;
    GLOAD_LDS(gB + (long)row * ldb + gs, Bd + r * 4096 + wb);
  }
}

__device__ __forceinline__ void gemm256(f32x4 (&acc)[4][4],
    const u16* Ag, int lda, const u16* Bg, int ldb, int nk,
    u16* As, u16* Bs, int tid) {
  const int lane = tid & 63, wid = tid >> 6;
  const int mq = wid >> 1, nh = wid & 1;
  const int rl = lane & 15, kg = lane >> 4;
  const int swz0 = ((kg ^ (rl & 7)) << 3);
  const int rbA = (mq >> 1) * 8192 + ((mq & 1) * 64 + rl) * 64;
  const int rbB = (nh * 64 + rl) * 64;

  stage256(Ag, lda, Bg, ldb, As, Bs, tid);                            // t=0
  if (nk > 1)
    stage256(Ag + 64, lda, Bg + 64, ldb, As + 16384, Bs + 8192, tid); // t=1
  int bsel = 0;
  for (int t = 0; t < nk; ++t) {
    if (t + 1 < nk) asm volatile("s_waitcnt vmcnt(6)" ::: "memory");
    else            asm volatile("s_waitcnt vmcnt(0)" ::: "memory");
    __builtin_amdgcn_s_barrier();              // stage(t) visible to all waves
    if (t + 2 < nk) {
      int nb = bsel + 2; if (nb >= 3) nb -= 3;
      stage256(Ag + (long)(t + 2) * 64, lda, Bg + (long)(t + 2) * 64, ldb,
               As + nb * 16384, Bs + nb * 8192, tid);
    }
    const u16* ab = As + bsel * 16384 + rbA;
    const u16* bb = Bs + bsel * 8192 + rbB;
    const int s0 = swz0, s1 = swz0 ^ 32;
    bf16x8 a0[4], b0[4], a1[4], b1[4];
#pragma unroll
    for (int i = 0; i < 4; i++) a0[i] = ds128(ab + i * 1024 + s0);
#pragma unroll
    for (int j = 0; j < 4; j++) b0[j] = ds128(bb + j * 1024 + s0);
#pragma unroll
    for (int i = 0; i < 4; i++) a1[i] = ds128(ab + i * 1024 + s1);
#pragma unroll
    for (int j = 0; j < 4; j++) b1[j] = ds128(bb + j * 1024 + s1);
    asm volatile("s_waitcnt lgkmcnt(8)" ::: "memory");   // kk0 reads landed
    __builtin_amdgcn_sched_barrier(0);
    __builtin_amdgcn_s_setprio(1);
#pragma unroll
    for (int i = 0; i < 4; i++)
#pragma unroll
      for (int j = 0; j < 4; j++)
        acc[i][j] = __builtin_amdgcn_mfma_f32_16x16x32_bf16(a0[i], b0[j], acc[i][j], 0, 0, 0);
    __builtin_amdgcn_s_setprio(0);
    asm volatile("s_waitcnt lgkmcnt(0)" ::: "memory");   // kk1 reads landed
    __builtin_amdgcn_sched_barrier(0);
    __builtin_amdgcn_s_setprio(1);
#pragma unroll
    for (int i = 0; i < 4; i++)
#pragma unroll
      for (int j = 0; j < 4; j++)
        acc[i][j] = __builtin_amdgcn_mfma_f32_16x16x32_bf16(a1[i], b1[j], acc[i][j], 0, 0, 0);
    __builtin_amdgcn_s_setprio(0);
    __builtin_amdgcn_sched_barrier(0);
    bsel = bsel + 1; if (bsel == 3) bsel = 0;
  }
}

// ---------------- conversion kernels ----------------
__global__ __launch_bounds__(256) void k_cvt2(const float* __restrict__ inX,
                                              const float* __restrict__ inY,
                                              u16* __restrict__ oX, u16* __restrict__ oY,
                                              int n8) {
  int i = blockIdx.x * 256 + threadIdx.x;
  const float* in = (i < n8) ? inX : inY;
  u16* out = (i < n8) ? oX : oY;
  int k = (i < n8) ? i : i - n8;
  const float4* pf = (const float4*)in + (long)k * 2;
  float4 a = pf[0], b = pf[1];
  u16x8 o;
  o[0] = f2bf(a.x); o[1] = f2bf(a.y); o[2] = f2bf(a.z); o[3] = f2bf(a.w);
  o[4] = f2bf(b.x); o[5] = f2bf(b.y); o[6] = f2bf(b.z); o[7] = f2bf(b.w);
  *((u16x8*)out + k) = o;
}

struct P6 { const float* p[6]; };
struct O6 { u16* p[6]; };

__global__ __launch_bounds__(256) void k_cvt_w(P6 w, u16* __restrict__ out) {
  int z = blockIdx.y;
  int i = blockIdx.x * 256 + threadIdx.x;
  const float4* pf = (const float4*)w.p[z] + (long)i * 2;
  float4 a = pf[0], b = pf[1];
  u16x8 o;
  o[0] = f2bf(a.x); o[1] = f2bf(a.y); o[2] = f2bf(a.z); o[3] = f2bf(a.w);
  o[4] = f2bf(b.x); o[5] = f2bf(b.y); o[6] = f2bf(b.z); o[7] = f2bf(b.w);
  *((u16x8*)(out + (long)z * 262144) + i) = o;
}

// ---------------- projections (old core, 1D bm-chunked grid) ----------------
__global__ __launch_bounds__(256) void k_proj(const u16* __restrict__ Xb, const u16* __restrict__ Yb,
                                              const u16* __restrict__ Wb, P6 bias, O6 dst) {
  __shared__ u16 As[12288], Bs[12288];
  int x = blockIdx.x;
  int swz = (x & 7) * 384 + (x >> 3);
  int bm = swz / 24;
  int r  = swz - bm * 24;
  int z = r >> 2, bn = r & 3;
  int tid = threadIdx.x, wave = tid >> 6, lane = tid & 63;
  const u16* Ag = (z < 3 ? Xb : Yb) + (long)bm * 128 * 512;
  const u16* Bg = Wb + (long)z * 262144 + (long)bn * 128 * 512;
  f32x4 acc[4][4] = {};
  gemm_seg(acc, Ag, Bg, 512, 512, 16, As, Bs, wave, lane);
  const float* bi = bias.p[z];
  u16* D = dst.p[z];
  int wr = (wave >> 1) << 6, wc = (wave & 1) << 6;
  int row0 = bm * 128 + wr + ((lane >> 4) << 2);
  int col0 = bn * 128 + wc + (lane & 15);
  float bj[4];
#pragma unroll
  for (int j = 0; j < 4; j++) bj[j] = bi[col0 + (j << 4)];
#pragma unroll
  for (int i = 0; i < 4; i++)
#pragma unroll
    for (int j = 0; j < 4; j++)
#pragma unroll
      for (int rr = 0; rr < 4; rr++)
        D[(long)(row0 + (i << 4) + rr) * 512 + col0 + (j << 4)] = f2bf(acc[i][j][rr] + bj[j]);
}

// ---------------- scores (new core): XCD chunk = one batch b ----------------
__global__ __launch_bounds__(512) void k_s(const u16* __restrict__ Q, const u16* __restrict__ K,
                                           u16* __restrict__ S) {
  __shared__ u16 As[49152], Bs[24576];
  int x = blockIdx.x;
  int swz = (x & 7) * 128 + (x >> 3);        // 1024 blocks, chunk=128 = one b
  int bn = swz & 15, bm = (swz >> 4) & 7, b = swz >> 7;
  int tid = threadIdx.x;
  const u16* Ag = Q + (long)b * 1048576 + (long)bm * 256 * 512;
  const u16* Bg = K + (long)b * 1048576 + (long)bn * 128 * 512;
  f32x4 acc[4][4] = {};
  gemm256(acc, Ag, 512, Bg, 512, 8, As, Bs, tid);
  u16* D = S + (long)b * 4194304;
  const float scale = 0.04419417382415922f;  // 1/sqrt(512)
  int lane = tid & 63, wid = tid >> 6;
  int mq = wid >> 1, nh = wid & 1;
  int row0 = bm * 256 + mq * 64 + ((lane >> 4) << 2);
  int col0 = bn * 128 + nh * 64 + (lane & 15);
#pragma unroll
  for (int i = 0; i < 4; i++)
#pragma unroll
    for (int j = 0; j < 4; j++)
#pragma unroll
      for (int rr = 0; rr < 4; rr++)
        D[(long)(row0 + (i << 4) + rr) * 2048 + col0 + (j << 4)] = f2bf(acc[i][j][rr] * scale);
}

// ---------------- softmax over batch axis ----------------
__global__ __launch_bounds__(256) void k_softmax(u16* __restrict__ S) {
  int idx = blockIdx.x * 256 + threadIdx.x;
  u16x8 v[8];
#pragma unroll
  for (int b = 0; b < 8; b++) v[b] = *((const u16x8*)(S + (long)b * 4194304) + idx);
#pragma unroll
  for (int j = 0; j < 8; j++) {
    float e[8], m = -1e30f;
#pragma unroll
    for (int b = 0; b < 8; b++) { e[b] = bf2f(v[b][j]); m = fmaxf(m, e[b]); }
    float s = 0.f;
#pragma unroll
    for (int b = 0; b < 8; b++) { e[b] = __expf(e[b] - m); s += e[b]; }
    float inv = 1.0f / s;
#pragma unroll
    for (int b = 0; b < 8; b++) v[b][j] = f2bf(e[b] * inv);
  }
#pragma unroll
  for (int b = 0; b < 8; b++) *((u16x8*)(S + (long)b * 4194304) + idx) = v[b];
}

// ---------------- V transpose ----------------
__global__ __launch_bounds__(256) void k_tr(const u16* __restrict__ V1, const u16* __restrict__ V2,
                                            u16* __restrict__ T1, u16* __restrict__ T2) {
  __shared__ u16 tile[64][65];
  int z = blockIdx.z;
  const u16* src = (z < 8 ? V1 : V2) + (long)(z & 7) * 1048576;
  u16*       dst = (z < 8 ? T1 : T2) + (long)(z & 7) * 1048576;
  int n0 = blockIdx.x * 64, d0 = blockIdx.y * 64;
  int t = threadIdx.x;
  int r = t >> 2, cs = (t & 3) * 16;
  const u16x8* sp = (const u16x8*)(src + (long)(n0 + r) * 512 + d0 + cs);
  u16x8 a = sp[0], b = sp[1];
#pragma unroll
  for (int jj = 0; jj < 8; jj++) { tile[r][cs + jj] = a[jj]; tile[r][cs + 8 + jj] = b[jj]; }
  __syncthreads();
  u16x8 o0, o1;
#pragma unroll
  for (int jj = 0; jj < 8; jj++) { o0[jj] = tile[cs + jj][r]; o1[jj] = tile[cs + 8 + jj][r]; }
  u16x8* op = (u16x8*)(dst + (long)(d0 + r) * 2048 + n0 + cs);
  op[0] = o0; op[1] = o1;
}

// ---------------- PV (new core): XCD chunk = one batch b ----------------
// mode 0: out = acc + X + Y ; mode 1: out += acc
__global__ __launch_bounds__(512) void k_pv(const u16* __restrict__ A, const u16* __restrict__ Vt,
                                            const float* __restrict__ X, const float* __restrict__ Y,
                                            float* __restrict__ out, int mode) {
  __shared__ u16 As[49152], Bs[24576];
  int x = blockIdx.x;
  int swz = (x & 7) * 32 + (x >> 3);         // 256 blocks, chunk=32 = one b
  int bn = swz & 3, bm = (swz >> 2) & 7, b = swz >> 5;
  int tid = threadIdx.x;
  const u16* Ag = A + (long)b * 4194304 + (long)bm * 256 * 2048;
  const u16* Bg = Vt + (long)b * 1048576 + (long)bn * 128 * 2048;
  f32x4 acc[4][4] = {};
  gemm256(acc, Ag, 2048, Bg, 2048, 32, As, Bs, tid);
  int lane = tid & 63, wid = tid >> 6;
  int mq = wid >> 1, nh = wid & 1;
  int row0 = bm * 256 + mq * 64 + ((lane >> 4) << 2);
  int col0 = bn * 128 + nh * 64 + (lane & 15);
  long base = (long)b * 1048576;
#pragma unroll
  for (int i = 0; i < 4; i++)
#pragma unroll
    for (int j = 0; j < 4; j++)
#pragma unroll
      for (int rr = 0; rr < 4; rr++) {
        long idx = base + (long)(row0 + (i << 4) + rr) * 512 + col0 + (j << 4);
        float v = acc[i][j][rr];
        out[idx] = mode ? (out[idx] + v) : (v + X[idx] + Y[idx]);
      }
}

extern "C" void kernel_launch(void* const* d_in, const int* in_sizes, int n_in,
                              void* d_out, int out_size, void* d_ws, size_t ws_size,
                              hipStream_t stream) {
  const float* X = (const float*)d_in[0];
  const float* Y = (const float*)d_in[1];
  P6 wp, bp;
  for (int i = 0; i < 6; i++) { wp.p[i] = (const float*)d_in[2 + 2 * i]; bp.p[i] = (const float*)d_in[3 + 2 * i]; }

  const long NX = 8L * 2048 * 512;
  const long NS = 8L * 2048 * 2048;
  u16* p = (u16*)d_ws;
  u16* Xb = p;  p += NX;                  // bf16 X (reused as Vt1)
  u16* Yb = p;  p += NX;                  // bf16 Y (reused as Vt2)
  u16* Wb = p;  p += 6L * 512 * 512;
  u16* Q1 = p;  p += NX;
  u16* K2 = p;  p += NX;
  u16* Q2 = p;  p += NX;
  u16* K1 = p;  p += NX;
  u16* Sb = p;  p += NS;
  u16* V1 = Sb;
  u16* V2 = Sb + NX;
  u16* Vt1 = Xb;
  u16* Vt2 = Yb;
  (void)ws_size; (void)in_sizes; (void)n_in; (void)out_size;

  dim3 T(256);
  k_cvt2<<<dim3(8192), T, 0, stream>>>(X, Y, Xb, Yb, (int)(NX / 8));
  k_cvt_w<<<dim3(128, 6), T, 0, stream>>>(wp, Wb);
  O6 dst; dst.p[0] = Q1; dst.p[1] = K1; dst.p[2] = V1; dst.p[3] = Q2; dst.p[4] = K2; dst.p[5] = V2;
  k_proj<<<dim3(3072), T, 0, stream>>>(Xb, Yb, Wb, bp, dst);
  k_tr<<<dim3(32, 8, 16), T, 0, stream>>>(V1, V2, Vt1, Vt2);
  // attention 2 first: S2 = Q2.K1^T, softmax over b, out = A2.V1 + X + Y
  k_s<<<dim3(1024), dim3(512), 0, stream>>>(Q2, K1, Sb);
  k_softmax<<<dim3(2048), T, 0, stream>>>(Sb);
  k_pv<<<dim3(256), dim3(512), 0, stream>>>(Sb, Vt1, X, Y, (float*)d_out, 0);
  // attention 1: S1 = Q1.K2^T, softmax, out += A1.V2
  k_s<<<dim3(1024), dim3(512), 0, stream>>>(Q1, K2, Sb);
  k_softmax<<<dim3(2048), T, 0, stream>>>(Sb);
  k_pv<<<dim3(256), dim3(512), 0, stream>>>(Sb, Vt2, X, Y, (float*)d_out, 1);
}